// Round 12
// baseline (623.539 us; speedup 1.0000x reference)
//
#include <hip/hip_runtime.h>
#include <hip/hip_bf16.h>

// Problem constants
#define CC 256      // channels
#define CKD 32      // q/k projection dim
#define NN 4096     // H*W
#define HH 64
#define WW 64
#define BB 4

#define LOG2E 1.44269504088896f
#define EXPSHIFT 23.0831203874f   // 16 * LOG2E

typedef __attribute__((ext_vector_type(8))) short short8;   // 8 bf16 (4 VGPRs)
typedef __attribute__((ext_vector_type(4))) float floatx4;  // MFMA C/D frag

__device__ __forceinline__ unsigned f2bf(float f) {
  union { float f; unsigned u; } v; v.f = f;
  unsigned r = v.u + 0x7fffu + ((v.u >> 16) & 1u);   // RNE
  return r >> 16;
}
__device__ __forceinline__ float fast_exp2(float x) {
#if __has_builtin(__builtin_amdgcn_exp2f)
  return __builtin_amdgcn_exp2f(x);
#else
  return __expf(x * 0.693147181f);
#endif
}
// pack two fp32 -> bf16 pair (low = a, high = b)
__device__ __forceinline__ unsigned pack2bf(float a, float b) {
  unsigned ua = __float_as_uint(a) + 0x8000u;
  unsigned ub = __float_as_uint(b) + 0x8000u;
  return __builtin_amdgcn_perm(ub, ua, 0x07060302u);
}

// LDS-only barrier: orders DS ops across waves WITHOUT draining vmcnt.
__device__ __forceinline__ void bar_lds() {
  asm volatile("s_waitcnt lgkmcnt(0)" ::: "memory");
  __builtin_amdgcn_s_barrier();
}

// ---------------------------------------------------------------------------
// Kernel 0: merged pack. z<8: pack x (fp32 [img][c][n]) -> Xp (bf16 [img][n][c]).
// z==8: pack conv weights Wp[tap][o][c] (tap 9 = 1x1), QKV weights
// Wqkv[inp][o=320][c] (q rows scaled by log2e), Bias[inp][320] (fp32).
// ---------------------------------------------------------------------------
__global__ __launch_bounds__(256) void pack_kernel(
    const float* __restrict__ x1, const float* __restrict__ x2,
    unsigned short* __restrict__ Xp,
    const float* __restrict__ wd1, const float* __restrict__ wd3,
    const float* __restrict__ wq1, const float* __restrict__ wk1,
    const float* __restrict__ wv1,
    const float* __restrict__ wq2, const float* __restrict__ wk2,
    const float* __restrict__ wv2,
    const float* __restrict__ bq1, const float* __restrict__ bk1,
    const float* __restrict__ bv1,
    const float* __restrict__ bq2, const float* __restrict__ bk2,
    const float* __restrict__ bv2,
    unsigned short* __restrict__ Wp, unsigned short* __restrict__ Wqkv,
    float* __restrict__ Bias) {
  const int t = threadIdx.x;
  __shared__ float tile[64][65];
  if (blockIdx.z < 8) {
    // ---- xpack ----
    const int nb = blockIdx.x, cbk = blockIdx.y, img = blockIdx.z;
    const float* X = ((img >> 2) ? x2 : x1) + (size_t)(img & 3) * CC * NN;
    const int n0 = nb * 64, c0 = cbk * 64;
    const int nl = t & 63, cl0 = t >> 6;
#pragma unroll
    for (int i = 0; i < 16; ++i)
      tile[cl0 + i * 4][nl] = X[(size_t)(c0 + cl0 + i * 4) * NN + n0 + nl];
    __syncthreads();
#pragma unroll
    for (int it = 0; it < 2; ++it) {
      int id = it * 256 + t;
      int nl2 = id >> 3, cc = id & 7;
      short8 v;
#pragma unroll
      for (int j = 0; j < 8; ++j) v[j] = (short)f2bf(tile[cc * 8 + j][nl2]);
      *(short8*)(Xp + (size_t)img * NN * CC + (size_t)(n0 + nl2) * CC + c0 + cc * 8) = v;
    }
  } else {
    // ---- wpack ----
    const int id = (blockIdx.y * 64 + blockIdx.x) * 256 + t;  // 0..65535
#pragma unroll
    for (int tap = 0; tap < 10; ++tap) {
      float v = (tap < 9) ? wd3[(size_t)id * 9 + tap] : wd1[id];
      Wp[(size_t)tap * (CC * CC) + id] = (unsigned short)f2bf(v);
    }
#pragma unroll
    for (int j = 0; j < 3; ++j) {
      int e = id + j * 65536;
      if (e < 2 * 320 * 256) {
        int inp = e / (320 * 256), rem = e % (320 * 256);
        int o = rem >> 8, c = rem & 255;
        float v;
        if (inp == 0)
          v = (o < 32) ? wq1[o * 256 + c] * LOG2E
              : (o < 64) ? wk1[(o - 32) * 256 + c] : wv1[(o - 64) * 256 + c];
        else
          v = (o < 32) ? wq2[o * 256 + c] * LOG2E
              : (o < 64) ? wk2[(o - 32) * 256 + c] : wv2[(o - 64) * 256 + c];
        Wqkv[e] = (unsigned short)f2bf(v);
      }
    }
    if (id < 640) {
      int inp = id / 320, o = id % 320;
      float v;
      if (inp == 0) v = (o < 32) ? bq1[o] * LOG2E
                        : (o < 64) ? bk1[o - 32] : bv1[o - 64];
      else          v = (o < 32) ? bq2[o] * LOG2E
                        : (o < 64) ? bk2[o - 32] : bv2[o - 64];
      Bias[id] = v;
    }
  }
}

// ---------------------------------------------------------------------------
// Kernel 1: MFMA projections. GEMM: [64 pix] x [320 o] x [K=256 c] per block.
// V is stored in sigma-permuted order (verified in R2): for j-tile t, group
// gi=h*4+gg holds, for channel c, 8 bf16 where element e sits at local pix
// h*32 + (e>>2)*16 + gg*4 + (e&3). This makes attn GEMM1's D-fragment
// directly consumable as GEMM2's A-fragment (k = g*8 + e).
// ---------------------------------------------------------------------------
__global__ __launch_bounds__(256) void proj_mfma_kernel(
    const unsigned short* __restrict__ Xp, const unsigned short* __restrict__ Wqkv,
    const float* __restrict__ Bias,
    unsigned short* __restrict__ Qp1, unsigned short* __restrict__ Kp1,
    unsigned short* __restrict__ Vp1,
    unsigned short* __restrict__ Qp2, unsigned short* __restrict__ Kp2,
    unsigned short* __restrict__ Vp2) {
  const int t = threadIdx.x;
  const int w = t >> 6, lane = t & 63;
  const int l15 = lane & 15, g = lane >> 4;
  const int img = blockIdx.x, pb = blockIdx.y;
  const int pix0 = pb * 64;
  const int inp = img >> 2, b = img & 3;
  const unsigned short* Xi = Xp + (size_t)img * NN * CC;
  const unsigned short* Wb = Wqkv + (size_t)inp * 320 * CC;
  const float* Bi = Bias + inp * 320;
  unsigned short* Qp = (inp ? Qp2 : Qp1) + (size_t)b * NN * CKD;
  unsigned short* Kp = (inp ? Kp2 : Kp1) + (size_t)b * NN * CKD;
  unsigned short* Vp = (inp ? Vp2 : Vp1) + (size_t)b * NN * CC;

  __shared__ unsigned short tile[320][72];   // [o][pix]

  floatx4 acc[4][5];
#pragma unroll
  for (int mf = 0; mf < 4; ++mf)
#pragma unroll
    for (int nf = 0; nf < 5; ++nf) acc[mf][nf] = (floatx4){0.f, 0.f, 0.f, 0.f};
  const int o0w = w * 80;

#pragma unroll
  for (int cb = 0; cb < 8; ++cb) {
    short8 a[4], bfr[5];
#pragma unroll
    for (int mf = 0; mf < 4; ++mf)
      a[mf] = *(const short8*)(Xi + (size_t)(pix0 + mf * 16 + l15) * CC + cb * 32 + g * 8);
#pragma unroll
    for (int nf = 0; nf < 5; ++nf)
      bfr[nf] = *(const short8*)(Wb + (size_t)(o0w + nf * 16 + l15) * CC + cb * 32 + g * 8);
#pragma unroll
    for (int nf = 0; nf < 5; ++nf)
#pragma unroll
      for (int mf = 0; mf < 4; ++mf)
        acc[mf][nf] = __builtin_amdgcn_mfma_f32_16x16x32_bf16(
            a[mf], bfr[nf], acc[mf][nf], 0, 0, 0);
  }

#pragma unroll
  for (int nf = 0; nf < 5; ++nf) {
    float bs = Bi[o0w + nf * 16 + l15];
#pragma unroll
    for (int mf = 0; mf < 4; ++mf) {
      uint2 pk;
      pk.x = f2bf(acc[mf][nf][0] + bs) | (f2bf(acc[mf][nf][1] + bs) << 16);
      pk.y = f2bf(acc[mf][nf][2] + bs) | (f2bf(acc[mf][nf][3] + bs) << 16);
      *(uint2*)&tile[o0w + nf * 16 + l15][mf * 16 + g * 4] = pk;
    }
  }
  __syncthreads();

  {
    const int pix = t >> 2, ch = t & 3;
    short8 vq, vk;
#pragma unroll
    for (int e = 0; e < 8; ++e) {
      vq[e] = (short)tile[ch * 8 + e][pix];
      vk[e] = (short)tile[32 + ch * 8 + e][pix];
    }
    *(short8*)(Qp + (size_t)(pix0 + pix) * CKD + ch * 8) = vq;
    *(short8*)(Kp + (size_t)(pix0 + pix) * CKD + ch * 8) = vk;
  }
  // V in sigma-layout: group gi = h*4+gg, element e -> pix h*32+(e>>2)*16+gg*4+(e&3)
#pragma unroll
  for (int gi = 0; gi < 8; ++gi) {
    const int h = gi >> 2, gg = gi & 3;
    uint2 lo = *(const uint2*)&tile[64 + t][h * 32 + gg * 4];        // e=0..3
    uint2 hi = *(const uint2*)&tile[64 + t][h * 32 + 16 + gg * 4];   // e=4..7
    uint4 vv = {lo.x, lo.y, hi.x, hi.y};
    *(uint4*)(Vp + (((size_t)(pix0 >> 3) + gi) * CC + t) * 8) = vv;
  }
}

// ---------------------------------------------------------------------------
// Kernel 2: fused flash attention + conv + epilogue.  (R12: barrier-free attn)
// grid (2 att, 4 b, 64 yblk), 256 thr, 2 blocks/CU.
// Row-slice decomposition: wave w owns output rows i0 + w*16..+15 x ALL 256
// channels. GEMM1 (4 MFMA/tile, non-redundant) produces P[j][i=w*16+l15]
// lane-local; sigma-V makes it directly the GEMM2 A-fragment -> P never
// touches LDS. j-loop has ZERO barriers / ZERO LDS. Two channel-half passes
// (c 0..127, 128..255) keep the V register window at 16 short8 (G1 redone
// per pass: +7% MFMA). acc[16] frags = 64 AGPR.
// Then: l (wave-local reduce, LDS transpose), seed acc *= 1/l, conv (xs
// staged; A = own 16 pixels, B = all 16 ch-tiles) accumulates into acc.
// ---------------------------------------------------------------------------
__global__ __launch_bounds__(256, 2) void attn_kernel(
    const unsigned short* __restrict__ Qp1, const unsigned short* __restrict__ Kp1,
    const unsigned short* __restrict__ Qp2, const unsigned short* __restrict__ Kp2,
    const unsigned short* __restrict__ Vp1, const unsigned short* __restrict__ Vp2,
    const unsigned short* __restrict__ Xp, const unsigned short* __restrict__ Wp,
    const float* __restrict__ bd1, const float* __restrict__ bd3,
    const float* __restrict__ x1, const float* __restrict__ x2,
    const float* __restrict__ g1, const float* __restrict__ g2,
    float* __restrict__ out) {
  const int t = threadIdx.x;
  const int w = t >> 6, lane = t & 63;
  const int l15 = lane & 15, g = lane >> 4;
  const int att = blockIdx.x, b = blockIdx.y;
  const int yblk = blockIdx.z;
  const int i0 = yblk * 64;

  const unsigned short *Qp, *Kp, *Vp; const float *x; float gamma; float* o;
  if (att == 0) { Qp = Qp1; Kp = Kp2; Vp = Vp2; x = x1; gamma = g1[0]; o = out; }
  else          { Qp = Qp2; Kp = Kp1; Vp = Vp1; x = x2; gamma = g2[0];
                  o = out + (size_t)BB * CC * NN; }
  Qp += (size_t)b * NN * CKD; Kp += (size_t)b * NN * CKD; Vp += (size_t)b * NN * CC;
  x += (size_t)b * CC * NN; o += (size_t)b * CC * NN;
  const unsigned short* Xi = Xp + (size_t)(att * 4 + b) * NN * CC;  // own image

  __shared__ unsigned short xs[3][66][72];  // conv pixel tile (Phase C only)
  __shared__ float l_s[64];

  // Q B-frag: wave w owns query rows i0 + w*16 + l15 (Q pre-scaled by log2e)
  short8 bq = *(const short8*)(Qp + (size_t)(i0 + w * 16 + l15) * CKD + g * 8);

  floatx4 acc[16];   // [c16]: ch c16*16+l15, row i0 + w*16 + g*4 + r
#pragma unroll
  for (int c16 = 0; c16 < 16; ++c16) acc[c16] = (floatx4){0.f, 0.f, 0.f, 0.f};
  float l_acc = 0.f;
  const floatx4 zinit = {-EXPSHIFT, -EXPSHIFT, -EXPSHIFT, -EXPSHIFT};

  short8 kr0[4], kr1[4], vA[8], vB[8], paA[2], paB[2];
  auto LOADK = [&](int tt, short8* d) {
    const unsigned short* kb = Kp + ((size_t)tt * 64 + l15) * CKD + g * 8;
#pragma unroll
    for (int js = 0; js < 4; ++js) d[js] = *(const short8*)(kb + js * 16 * CKD);
  };
  // V sigma-layout load: half h (j 0..31 / 32..63 of tile tt), 8 ch-tiles of
  // the current 128-ch half.
  auto LOADVH = [&](int tt, int h, int chalf, short8* d) {
    const unsigned short* vb = Vp + (((size_t)tt * 8 + h * 4 + g) * CC + chalf + l15) * 8;
#pragma unroll
    for (int c8 = 0; c8 < 8; ++c8)
      d[c8] = *(const short8*)(vb + (size_t)(c8 * 16) * 8);
  };
  // GEMM1: P for this wave's 16 rows, full 64-j tile; pack sigma-ordered
  // A-frags: pa[h] element e=jf*4+r holds P[j=(2h+jf)*16+g*4+r][i=w*16+l15].
  auto G1 = [&](const short8* kb, short8* pa) {
    floatx4 sA = __builtin_amdgcn_mfma_f32_16x16x32_bf16(kb[0], bq, zinit, 0, 0, 0);
    floatx4 sB = __builtin_amdgcn_mfma_f32_16x16x32_bf16(kb[1], bq, zinit, 0, 0, 0);
    floatx4 sC = __builtin_amdgcn_mfma_f32_16x16x32_bf16(kb[2], bq, zinit, 0, 0, 0);
    floatx4 sD = __builtin_amdgcn_mfma_f32_16x16x32_bf16(kb[3], bq, zinit, 0, 0, 0);
    float p0 = fast_exp2(sA[0]), p1 = fast_exp2(sA[1]);
    float p2 = fast_exp2(sA[2]), p3 = fast_exp2(sA[3]);
    float p4 = fast_exp2(sB[0]), p5 = fast_exp2(sB[1]);
    float p6 = fast_exp2(sB[2]), p7 = fast_exp2(sB[3]);
    float q0 = fast_exp2(sC[0]), q1 = fast_exp2(sC[1]);
    float q2 = fast_exp2(sC[2]), q3 = fast_exp2(sC[3]);
    float q4 = fast_exp2(sD[0]), q5 = fast_exp2(sD[1]);
    float q6 = fast_exp2(sD[2]), q7 = fast_exp2(sD[3]);
    l_acc += (((p0 + p1) + (p2 + p3)) + ((p4 + p5) + (p6 + p7)))
           + (((q0 + q1) + (q2 + q3)) + ((q4 + q5) + (q6 + q7)));
    union { unsigned u[4]; short8 s; } cv;
    cv.u[0] = pack2bf(p0, p1); cv.u[1] = pack2bf(p2, p3);
    cv.u[2] = pack2bf(p4, p5); cv.u[3] = pack2bf(p6, p7);
    pa[0] = cv.s;
    cv.u[0] = pack2bf(q0, q1); cv.u[1] = pack2bf(q2, q3);
    cv.u[2] = pack2bf(q4, q5); cv.u[3] = pack2bf(q6, q7);
    pa[1] = cv.s;
  };

  // ================= Phase B: barrier-free j-loop (2 channel-half passes) ===
#pragma unroll
  for (int p = 0; p < 2; ++p) {
    const int chalf = p * 128;
    const int ab = p * 8;          // acc base (compile-time after unroll)
    auto G2h = [&](const short8& pah, const short8* vb) {
      __builtin_amdgcn_s_setprio(1);
#pragma unroll
      for (int c8 = 0; c8 < 8; ++c8)
        acc[ab + c8] = __builtin_amdgcn_mfma_f32_16x16x32_bf16(
            pah, vb[c8], acc[ab + c8], 0, 0, 0);
      __builtin_amdgcn_s_setprio(0);
    };

    LOADK(0, kr0); LOADVH(0, 0, chalf, vA); LOADVH(0, 1, chalf, vB);
    LOADK(1, kr1);
    G1(kr0, paA);                      // P(0)
    LOADK(2, kr0);

    for (int jt = 0; jt < 64; jt += 2) {
      G1(kr1, paB);                    // P(jt+1)
      if (jt + 3 < 64) LOADK(jt + 3, kr1);
      G2h(paA[0], vA);                 // tile jt, j-half 0
      LOADVH(jt + 1, 0, chalf, vA);
      G2h(paA[1], vB);                 // tile jt, j-half 1
      LOADVH(jt + 1, 1, chalf, vB);
      if (jt + 2 < 64) {
        G1(kr0, paA);                  // P(jt+2)
        if (jt + 4 < 64) LOADK(jt + 4, kr0);
      }
      G2h(paB[0], vA);                 // tile jt+1, j-half 0
      if (jt + 2 < 64) LOADVH(jt + 2, 0, chalf, vA);
      G2h(paB[1], vB);                 // tile jt+1, j-half 1
      if (jt + 2 < 64) LOADVH(jt + 2, 1, chalf, vB);
    }

    if (p == 0) {
      // l complete after pass 0 (covers all 64 j-tiles); pass 1 recomputes
      // exp but its l_acc adds are never read.
      float v = l_acc;
      v += __shfl_xor(v, 16);
      v += __shfl_xor(v, 32);
      if (g == 0) l_s[w * 16 + l15] = v;
      bar_lds();
    }
  }

  // seed: acc *= 1/l  (conv then accumulates on top in the same layout)
  {
    float linv[4];
#pragma unroll
    for (int r = 0; r < 4; ++r) linv[r] = 1.f / l_s[w * 16 + g * 4 + r];
#pragma unroll
    for (int c16 = 0; c16 < 16; ++c16)
#pragma unroll
      for (int r = 0; r < 4; ++r) acc[c16][r] *= linv[r];
  }

  // ================= Phase C: conv accumulating into acc ================
  // A = own 16 pixels (rows w*16+l15), B = all 16 ch-tiles (n = och).
  for (int cb = 0; cb < 4; ++cb) {
    const int c0 = cb * 64;
    if (cb) bar_lds();   // prior tap reads of xs complete
#pragma unroll
    for (int it = 0; it < 7; ++it) {
      int id = it * 256 + t;
      if (id < 1584) {                    // 3*66*8 16B-chunks
        int r = id / 528, rem = id % 528;
        int col = rem >> 3, cc = rem & 7;
        int y = yblk - 1 + r, xx = col - 1;
        short8 v = {0, 0, 0, 0, 0, 0, 0, 0};
        if (y >= 0 && y < HH && xx >= 0 && xx < WW)
          v = *(const short8*)(Xi + (size_t)(y * WW + xx) * CC + c0 + cc * 8);
        *(short8*)&xs[r][col][cc * 8] = v;
      }
    }
    bar_lds();
#pragma unroll
    for (int tap = 0; tap < 10; ++tap) {
      const int dy = (tap < 9) ? tap / 3 - 1 : 0;
      const int dx = (tap < 9) ? tap % 3 - 1 : 0;
#pragma unroll
      for (int ks = 0; ks < 2; ++ks) {
        short8 af = *(const short8*)
            &xs[1 + dy][1 + w * 16 + l15 + dx][ks * 32 + g * 8];
        const unsigned short* wrow =
            Wp + ((size_t)tap * CC + l15) * CC + c0 + ks * 32 + g * 8;
#pragma unroll
        for (int c16 = 0; c16 < 16; ++c16) {
          short8 bw = *(const short8*)(wrow + (size_t)(c16 * 16) * CC);
          acc[c16] = __builtin_amdgcn_mfma_f32_16x16x32_bf16(
              af, bw, acc[c16], 0, 0, 0);
        }
      }
    }
  }

  // epilogue: out[c][i] = x + gamma*(acc + bias)   (acc = attn/l + conv)
#pragma unroll
  for (int c16 = 0; c16 < 16; ++c16) {
    int c = c16 * 16 + l15;
    float bs = bd1[c] + bd3[c];
    size_t base = (size_t)c * NN + i0 + w * 16 + g * 4;
    float4 xr = *(const float4*)(x + base);
    float4 ov;
    ov.x = xr.x + gamma * (acc[c16][0] + bs);
    ov.y = xr.y + gamma * (acc[c16][1] + bs);
    ov.z = xr.z + gamma * (acc[c16][2] + bs);
    ov.w = xr.w + gamma * (acc[c16][3] + bs);
    *(float4*)(o + base) = ov;
  }
}

// ---------------------------------------------------------------------------
extern "C" void kernel_launch(void* const* d_in, const int* in_sizes, int n_in,
                              void* d_out, int out_size, void* d_ws, size_t ws_size,
                              hipStream_t stream) {
  const float* x1  = (const float*)d_in[0];
  const float* x2  = (const float*)d_in[1];
  const float* wq1 = (const float*)d_in[2];
  const float* bq1 = (const float*)d_in[3];
  const float* wk1 = (const float*)d_in[4];
  const float* bk1 = (const float*)d_in[5];
  const float* wv1 = (const float*)d_in[6];
  const float* bv1 = (const float*)d_in[7];
  const float* wq2 = (const float*)d_in[8];
  const float* bq2 = (const float*)d_in[9];
  const float* wk2 = (const float*)d_in[10];
  const float* bk2 = (const float*)d_in[11];
  const float* wv2 = (const float*)d_in[12];
  const float* bv2 = (const float*)d_in[13];
  const float* wd1 = (const float*)d_in[14];
  const float* bd1 = (const float*)d_in[15];
  const float* wd3 = (const float*)d_in[16];
  const float* bd3 = (const float*)d_in[17];
  const float* g1  = (const float*)d_in[18];
  const float* g2  = (const float*)d_in[19];
  float* out = (float*)d_out;

  // workspace layout (bytes)
  const size_t QB = (size_t)BB * NN * CKD * 2;     // 1 MB each
  const size_t VB = (size_t)BB * NN * CC * 2;      // 8 MB each
  const size_t XB = (size_t)2 * BB * NN * CC * 2;  // 16 MB
  const size_t WPB = (size_t)10 * CC * CC * 2;     // 1.31 MB
  const size_t WQB = (size_t)2 * 320 * CC * 2;     // 320 KB
  char* base = (char*)d_ws;
  unsigned short* Qp1 = (unsigned short*)(base);
  unsigned short* Kp1 = (unsigned short*)(base + QB);
  unsigned short* Qp2 = (unsigned short*)(base + 2 * QB);
  unsigned short* Kp2 = (unsigned short*)(base + 3 * QB);
  unsigned short* Vp1 = (unsigned short*)(base + 4 * QB);
  unsigned short* Vp2 = (unsigned short*)(base + 4 * QB + VB);
  unsigned short* Xp  = (unsigned short*)(base + 4 * QB + 2 * VB);
  unsigned short* Wp  = (unsigned short*)(base + 4 * QB + 2 * VB + XB);
  unsigned short* Wqkv = (unsigned short*)(base + 4 * QB + 2 * VB + XB + WPB);
  float* Bias = (float*)(base + 4 * QB + 2 * VB + XB + WPB + WQB);

  pack_kernel<<<dim3(NN / 64, CC / 64, 9), 256, 0, stream>>>(
      x1, x2, Xp, wd1, wd3, wq1, wk1, wv1, wq2, wk2, wv2,
      bq1, bk1, bv1, bq2, bk2, bv2, Wp, Wqkv, Bias);

  proj_mfma_kernel<<<dim3(2 * BB, NN / 64), 256, 0, stream>>>(
      Xp, Wqkv, Bias, Qp1, Kp1, Vp1, Qp2, Kp2, Vp2);

  attn_kernel<<<dim3(2, BB, NN / 64), 256, 0, stream>>>(
      Qp1, Kp1, Qp2, Kp2, Vp1, Vp2, Xp, Wp, bd1, bd3, x1, x2, g1, g2, out);
}

// Round 14
// 506.337 us; speedup vs baseline: 1.2315x; 1.2315x over previous
//
#include <hip/hip_runtime.h>
#include <hip/hip_bf16.h>

// Problem constants
#define CC 256      // channels
#define CKD 32      // q/k projection dim
#define NN 4096     // H*W
#define HH 64
#define WW 64
#define BB 4

#define LOG2E 1.44269504088896f
#define EXPSHIFT 23.0831203874f   // 16 * LOG2E

typedef __attribute__((ext_vector_type(8))) short short8;   // 8 bf16 (4 VGPRs)
typedef __attribute__((ext_vector_type(4))) float floatx4;  // MFMA C/D frag

__device__ __forceinline__ unsigned f2bf(float f) {
  union { float f; unsigned u; } v; v.f = f;
  unsigned r = v.u + 0x7fffu + ((v.u >> 16) & 1u);   // RNE
  return r >> 16;
}
__device__ __forceinline__ float fast_exp2(float x) {
#if __has_builtin(__builtin_amdgcn_exp2f)
  return __builtin_amdgcn_exp2f(x);
#else
  return __expf(x * 0.693147181f);
#endif
}

// LDS-only barrier: orders DS ops across waves WITHOUT draining vmcnt.
__device__ __forceinline__ void bar_lds() {
  asm volatile("s_waitcnt lgkmcnt(0)" ::: "memory");
  __builtin_amdgcn_s_barrier();
}

// ---------------------------------------------------------------------------
// Kernel 0: merged pack. z<8: pack x (fp32 [img][c][n]) -> Xp (bf16 [img][n][c]).
// z==8: pack conv weights Wp[tap][o][c] (tap 9 = 1x1), QKV weights
// Wqkv[inp][o=320][c] (q rows scaled by log2e), Bias[inp][320] (fp32).
// ---------------------------------------------------------------------------
__global__ __launch_bounds__(256) void pack_kernel(
    const float* __restrict__ x1, const float* __restrict__ x2,
    unsigned short* __restrict__ Xp,
    const float* __restrict__ wd1, const float* __restrict__ wd3,
    const float* __restrict__ wq1, const float* __restrict__ wk1,
    const float* __restrict__ wv1,
    const float* __restrict__ wq2, const float* __restrict__ wk2,
    const float* __restrict__ wv2,
    const float* __restrict__ bq1, const float* __restrict__ bk1,
    const float* __restrict__ bv1,
    const float* __restrict__ bq2, const float* __restrict__ bk2,
    const float* __restrict__ bv2,
    unsigned short* __restrict__ Wp, unsigned short* __restrict__ Wqkv,
    float* __restrict__ Bias) {
  const int t = threadIdx.x;
  __shared__ float tile[64][65];
  if (blockIdx.z < 8) {
    // ---- xpack ----
    const int nb = blockIdx.x, cbk = blockIdx.y, img = blockIdx.z;
    const float* X = ((img >> 2) ? x2 : x1) + (size_t)(img & 3) * CC * NN;
    const int n0 = nb * 64, c0 = cbk * 64;
    const int nl = t & 63, cl0 = t >> 6;
#pragma unroll
    for (int i = 0; i < 16; ++i)
      tile[cl0 + i * 4][nl] = X[(size_t)(c0 + cl0 + i * 4) * NN + n0 + nl];
    __syncthreads();
#pragma unroll
    for (int it = 0; it < 2; ++it) {
      int id = it * 256 + t;
      int nl2 = id >> 3, cc = id & 7;
      short8 v;
#pragma unroll
      for (int j = 0; j < 8; ++j) v[j] = (short)f2bf(tile[cc * 8 + j][nl2]);
      *(short8*)(Xp + (size_t)img * NN * CC + (size_t)(n0 + nl2) * CC + c0 + cc * 8) = v;
    }
  } else {
    // ---- wpack ----
    const int id = (blockIdx.y * 64 + blockIdx.x) * 256 + t;  // 0..65535
#pragma unroll
    for (int tap = 0; tap < 10; ++tap) {
      float v = (tap < 9) ? wd3[(size_t)id * 9 + tap] : wd1[id];
      Wp[(size_t)tap * (CC * CC) + id] = (unsigned short)f2bf(v);
    }
#pragma unroll
    for (int j = 0; j < 3; ++j) {
      int e = id + j * 65536;
      if (e < 2 * 320 * 256) {
        int inp = e / (320 * 256), rem = e % (320 * 256);
        int o = rem >> 8, c = rem & 255;
        float v;
        if (inp == 0)
          v = (o < 32) ? wq1[o * 256 + c] * LOG2E
              : (o < 64) ? wk1[(o - 32) * 256 + c] : wv1[(o - 64) * 256 + c];
        else
          v = (o < 32) ? wq2[o * 256 + c] * LOG2E
              : (o < 64) ? wk2[(o - 32) * 256 + c] : wv2[(o - 64) * 256 + c];
        Wqkv[e] = (unsigned short)f2bf(v);
      }
    }
    if (id < 640) {
      int inp = id / 320, o = id % 320;
      float v;
      if (inp == 0) v = (o < 32) ? bq1[o] * LOG2E
                        : (o < 64) ? bk1[o - 32] : bv1[o - 64];
      else          v = (o < 32) ? bq2[o] * LOG2E
                        : (o < 64) ? bk2[o - 32] : bv2[o - 64];
      Bias[id] = v;
    }
  }
}

// ---------------------------------------------------------------------------
// Kernel 1: MFMA projections. GEMM: [64 pix] x [320 o] x [K=256 c] per block.
// (plain V layout, as verified through R9)
// ---------------------------------------------------------------------------
__global__ __launch_bounds__(256) void proj_mfma_kernel(
    const unsigned short* __restrict__ Xp, const unsigned short* __restrict__ Wqkv,
    const float* __restrict__ Bias,
    unsigned short* __restrict__ Qp1, unsigned short* __restrict__ Kp1,
    unsigned short* __restrict__ Vp1,
    unsigned short* __restrict__ Qp2, unsigned short* __restrict__ Kp2,
    unsigned short* __restrict__ Vp2) {
  const int t = threadIdx.x;
  const int w = t >> 6, lane = t & 63;
  const int l15 = lane & 15, g = lane >> 4;
  const int img = blockIdx.x, pb = blockIdx.y;
  const int pix0 = pb * 64;
  const int inp = img >> 2, b = img & 3;
  const unsigned short* Xi = Xp + (size_t)img * NN * CC;
  const unsigned short* Wb = Wqkv + (size_t)inp * 320 * CC;
  const float* Bi = Bias + inp * 320;
  unsigned short* Qp = (inp ? Qp2 : Qp1) + (size_t)b * NN * CKD;
  unsigned short* Kp = (inp ? Kp2 : Kp1) + (size_t)b * NN * CKD;
  unsigned short* Vp = (inp ? Vp2 : Vp1) + (size_t)b * NN * CC;

  __shared__ unsigned short tile[320][72];   // [o][pix]

  floatx4 acc[4][5];
#pragma unroll
  for (int mf = 0; mf < 4; ++mf)
#pragma unroll
    for (int nf = 0; nf < 5; ++nf) acc[mf][nf] = (floatx4){0.f, 0.f, 0.f, 0.f};
  const int o0w = w * 80;

#pragma unroll
  for (int cb = 0; cb < 8; ++cb) {
    short8 a[4], bfr[5];
#pragma unroll
    for (int mf = 0; mf < 4; ++mf)
      a[mf] = *(const short8*)(Xi + (size_t)(pix0 + mf * 16 + l15) * CC + cb * 32 + g * 8);
#pragma unroll
    for (int nf = 0; nf < 5; ++nf)
      bfr[nf] = *(const short8*)(Wb + (size_t)(o0w + nf * 16 + l15) * CC + cb * 32 + g * 8);
#pragma unroll
    for (int nf = 0; nf < 5; ++nf)
#pragma unroll
      for (int mf = 0; mf < 4; ++mf)
        acc[mf][nf] = __builtin_amdgcn_mfma_f32_16x16x32_bf16(
            a[mf], bfr[nf], acc[mf][nf], 0, 0, 0);
  }

#pragma unroll
  for (int nf = 0; nf < 5; ++nf) {
    float bs = Bi[o0w + nf * 16 + l15];
#pragma unroll
    for (int mf = 0; mf < 4; ++mf) {
      uint2 pk;
      pk.x = f2bf(acc[mf][nf][0] + bs) | (f2bf(acc[mf][nf][1] + bs) << 16);
      pk.y = f2bf(acc[mf][nf][2] + bs) | (f2bf(acc[mf][nf][3] + bs) << 16);
      *(uint2*)&tile[o0w + nf * 16 + l15][mf * 16 + g * 4] = pk;
    }
  }
  __syncthreads();

  {
    const int pix = t >> 2, ch = t & 3;
    short8 vq, vk;
#pragma unroll
    for (int e = 0; e < 8; ++e) {
      vq[e] = (short)tile[ch * 8 + e][pix];
      vk[e] = (short)tile[32 + ch * 8 + e][pix];
    }
    *(short8*)(Qp + (size_t)(pix0 + pix) * CKD + ch * 8) = vq;
    *(short8*)(Kp + (size_t)(pix0 + pix) * CKD + ch * 8) = vk;
  }
#pragma unroll
  for (int it = 0; it < 8; ++it) {
    short8 vv = *(const short8*)&tile[64 + t][it * 8];
    *(short8*)(Vp + ((size_t)((pix0 >> 3) + it) * CC + t) * 8) = vv;
  }
}

// ---------------------------------------------------------------------------
// Kernel 2: fused flash attention + INTERLEAVED conv + epilogue.  (R13)
// grid (2 att, 4 b, 64 yblk), 256 thr, 2 blocks/CU.
// R9's j-loop (4 ps slots, 1 bar_lds / 2 tiles, setprio) PLUS a conv slice
// per region into a SEPARATE accumulator cac[4][4] (+64 AGPR; total ~242
// regs, still 2 waves/SIMD). Region r (=jt/2): cb = r/8; r%8==0 stages the
// xs tile for cb; else 3 of the 20 (tap,ks) units. The per-region barrier
// orders stage vs tap-reads. Conv MFMAs are independent of the attn chain
// -> they fill the dependency bubbles that pinned MfmaUtil at ~30%.
// kr single-buffered, V as JIT half-buffers vA/vB (register budget).
// Epilogue: out = x + gamma*(acc/l + cac + bias).
// ---------------------------------------------------------------------------
__global__ __launch_bounds__(256, 2) void attn_kernel(
    const unsigned short* __restrict__ Qp1, const unsigned short* __restrict__ Kp1,
    const unsigned short* __restrict__ Qp2, const unsigned short* __restrict__ Kp2,
    const unsigned short* __restrict__ Vp1, const unsigned short* __restrict__ Vp2,
    const unsigned short* __restrict__ Xp, const unsigned short* __restrict__ Wp,
    const float* __restrict__ bd1, const float* __restrict__ bd3,
    const float* __restrict__ x1, const float* __restrict__ x2,
    const float* __restrict__ g1, const float* __restrict__ g2,
    float* __restrict__ out) {
  const int t = threadIdx.x;
  const int w = t >> 6, lane = t & 63;
  const int l15 = lane & 15, g = lane >> 4;
  const int att = blockIdx.x, b = blockIdx.y;
  const int yblk = blockIdx.z;
  const int i0 = yblk * 64;

  const unsigned short *Qp, *Kp, *Vp; const float *x; float gamma; float* o;
  if (att == 0) { Qp = Qp1; Kp = Kp2; Vp = Vp2; x = x1; gamma = g1[0]; o = out; }
  else          { Qp = Qp2; Kp = Kp1; Vp = Vp1; x = x2; gamma = g2[0];
                  o = out + (size_t)BB * CC * NN; }
  Qp += (size_t)b * NN * CKD; Kp += (size_t)b * NN * CKD; Vp += (size_t)b * NN * CC;
  x += (size_t)b * CC * NN; o += (size_t)b * CC * NN;
  const unsigned short* Xi = Xp + (size_t)(att * 4 + b) * NN * CC;  // own image

  __shared__ unsigned short ps[4][64][72];                 // attn P 4-buf (36.9KB)
  __shared__ union {
    unsigned short xs[3][66][72];                          // conv tile (28.5KB)
    float l_s[64];                                         // reused after loop
  } u2;

  // Q B-frag (held whole kernel); Q is pre-scaled by log2e
  short8 bq = *(const short8*)(Qp + (size_t)(i0 + w * 16 + l15) * CKD + g * 8);

  floatx4 acc[4][4];   // attention accumulator
  floatx4 cac[4][4];   // conv accumulator (independent chains)
#pragma unroll
  for (int a = 0; a < 4; ++a)
#pragma unroll
    for (int c = 0; c < 4; ++c) {
      acc[a][c] = (floatx4){0.f, 0.f, 0.f, 0.f};
      cac[a][c] = (floatx4){0.f, 0.f, 0.f, 0.f};
    }
  float l_acc = 0.f;
  const floatx4 zinit = {-EXPSHIFT, -EXPSHIFT, -EXPSHIFT, -EXPSHIFT};

  short8 kr[4], vA[4], vB[4];
  auto LOADK = [&](int tt) {
    const unsigned short* kb = Kp + ((size_t)tt * 64 + l15) * CKD + g * 8;
#pragma unroll
    for (int js = 0; js < 4; ++js) kr[js] = *(const short8*)(kb + js * 16 * CKD);
  };
  auto LOADVH = [&](int tt, int ks, short8* d) {
#pragma unroll
    for (int cs = 0; cs < 4; ++cs)
      d[cs] = *(const short8*)(Vp +
          (((size_t)tt * 8 + ks * 4 + g) * CC + (w * 64 + cs * 16 + l15)) * 8);
  };
  auto GEMM1 = [&](unsigned short (*psb)[72]) {
#pragma unroll
    for (int js = 0; js < 4; ++js) {
      floatx4 s = __builtin_amdgcn_mfma_f32_16x16x32_bf16(kr[js], bq, zinit, 0, 0, 0);
      float p0 = fast_exp2(s[0]);
      float p1 = fast_exp2(s[1]);
      float p2 = fast_exp2(s[2]);
      float p3 = fast_exp2(s[3]);
      l_acc += (p0 + p1) + (p2 + p3);
      unsigned u0 = __float_as_uint(p0) + 0x8000u;
      unsigned u1 = __float_as_uint(p1) + 0x8000u;
      unsigned u2v = __float_as_uint(p2) + 0x8000u;
      unsigned u3 = __float_as_uint(p3) + 0x8000u;
      uint2 pk;
      pk.x = __builtin_amdgcn_perm(u1, u0, 0x07060302u);
      pk.y = __builtin_amdgcn_perm(u3, u2v, 0x07060302u);
      *(uint2*)&psb[w * 16 + l15][js * 16 + g * 4] = pk;
    }
  };
  auto G2ks = [&](int ks, const short8* vb, unsigned short (*psb)[72]) {
    short8 ap[4];
#pragma unroll
    for (int isub = 0; isub < 4; ++isub)
      ap[isub] = *(const short8*)&psb[isub * 16 + l15][ks * 32 + g * 8];
    __builtin_amdgcn_s_setprio(1);
#pragma unroll
    for (int cs = 0; cs < 4; ++cs)
#pragma unroll
      for (int isub = 0; isub < 4; ++isub)
        acc[isub][cs] = __builtin_amdgcn_mfma_f32_16x16x32_bf16(
            ap[isub], vb[cs], acc[isub][cs], 0, 0, 0);
    __builtin_amdgcn_s_setprio(0);
  };

  // ================= prologue =================
  LOADK(0); LOADVH(0, 0, vA); LOADVH(0, 1, vB);
  GEMM1(ps[0]);          // consumes K(0)
  LOADK(1);
  GEMM1(ps[1]);          // consumes K(1)
  LOADK(2);
  bar_lds();

  // ============ main loop: 32 regions = attn 2-tiles + conv slice ==========
  for (int jt = 0; jt < 64; jt += 2) {
    const int r = jt >> 1;
    const int cb = r >> 3, rc = r & 7;
    const int c0 = cb * 64;

    // ---- conv slice ----
    if (rc == 0) {
      // stage xs tile for this cb (prev region's barrier ended prior taps)
#pragma unroll
      for (int it = 0; it < 7; ++it) {
        int id = it * 256 + t;
        if (id < 1584) {                    // 3*66*8 16B-chunks
          int rr = id / 528, rem = id % 528;
          int col = rem >> 3, ccc = rem & 7;
          int y = yblk - 1 + rr, xx = col - 1;
          short8 v = {0, 0, 0, 0, 0, 0, 0, 0};
          if (y >= 0 && y < HH && xx >= 0 && xx < WW)
            v = *(const short8*)(Xi + (size_t)(y * WW + xx) * CC + c0 + ccc * 8);
          *(short8*)&u2.xs[rr][col][ccc * 8] = v;
        }
      }
    } else {
#pragma unroll
      for (int k = 0; k < 3; ++k) {
        const int uu = (rc - 1) * 3 + k;
        if (uu < 20) {
          const int tap = uu >> 1, ks2 = uu & 1;
          const int dy = (tap < 9) ? tap / 3 - 1 : 0;
          const int dx = (tap < 9) ? tap % 3 - 1 : 0;
          const unsigned short* wrow =
              Wp + ((size_t)tap * CC + w * 64 + l15) * CC + c0 + g * 8;
          short8 af[4], bw[4];
#pragma unroll
          for (int pm = 0; pm < 4; ++pm)
            af[pm] = *(const short8*)
                &u2.xs[1 + dy][1 + pm * 16 + l15 + dx][ks2 * 32 + g * 8];
#pragma unroll
          for (int on = 0; on < 4; ++on)
            bw[on] = *(const short8*)(wrow + (size_t)(on * 16) * CC + ks2 * 32);
#pragma unroll
          for (int pm = 0; pm < 4; ++pm)
#pragma unroll
            for (int on = 0; on < 4; ++on)
              cac[pm][on] = __builtin_amdgcn_mfma_f32_16x16x32_bf16(
                  af[pm], bw[on], cac[pm][on], 0, 0, 0);
        }
      }
    }

    // ---- attn 2 tiles (R9 schedule; kr single-buf, V JIT halves) ----
    if (jt + 2 < 64) {
      GEMM1(ps[(jt + 2) & 3]);                 // consumes kr = K(jt+2)
      if (jt + 3 < 64) LOADK(jt + 3);
    }
    G2ks(0, vA, ps[jt & 3]);   LOADVH(jt + 1, 0, vA);
    G2ks(1, vB, ps[jt & 3]);   LOADVH(jt + 1, 1, vB);
    if (jt + 3 < 64) {
      GEMM1(ps[(jt + 3) & 3]);                 // consumes kr = K(jt+3)
      if (jt + 4 < 64) LOADK(jt + 4);
    }
    G2ks(0, vA, ps[(jt + 1) & 3]); if (jt + 2 < 64) LOADVH(jt + 2, 0, vA);
    G2ks(1, vB, ps[(jt + 1) & 3]); if (jt + 2 < 64) LOADVH(jt + 2, 1, vB);
    bar_lds();
  }

  // l: reduce across g (lane bits 4,5); xs no longer read -> reuse as l_s
  l_acc += __shfl_xor(l_acc, 16);
  l_acc += __shfl_xor(l_acc, 32);
  if (g == 0) u2.l_s[w * 16 + l15] = l_acc;
  bar_lds();

  // epilogue: out[c][i] = x + gamma*(acc/l + cac + bias)
#pragma unroll
  for (int isub = 0; isub < 4; ++isub) {
    float linv[4];
#pragma unroll
    for (int r2 = 0; r2 < 4; ++r2) linv[r2] = 1.f / u2.l_s[isub * 16 + g * 4 + r2];
#pragma unroll
    for (int cs = 0; cs < 4; ++cs) {
      int c = w * 64 + cs * 16 + l15;
      float bs = bd1[c] + bd3[c];
      size_t base = (size_t)c * NN + i0 + isub * 16 + g * 4;
      float4 xr = *(const float4*)(x + base);
      float4 ov;
      ov.x = xr.x + gamma * (acc[isub][cs][0] * linv[0] + cac[isub][cs][0] + bs);
      ov.y = xr.y + gamma * (acc[isub][cs][1] * linv[1] + cac[isub][cs][1] + bs);
      ov.z = xr.z + gamma * (acc[isub][cs][2] * linv[2] + cac[isub][cs][2] + bs);
      ov.w = xr.w + gamma * (acc[isub][cs][3] * linv[3] + cac[isub][cs][3] + bs);
      *(float4*)(o + base) = ov;
    }
  }
}

// ---------------------------------------------------------------------------
extern "C" void kernel_launch(void* const* d_in, const int* in_sizes, int n_in,
                              void* d_out, int out_size, void* d_ws, size_t ws_size,
                              hipStream_t stream) {
  const float* x1  = (const float*)d_in[0];
  const float* x2  = (const float*)d_in[1];
  const float* wq1 = (const float*)d_in[2];
  const float* bq1 = (const float*)d_in[3];
  const float* wk1 = (const float*)d_in[4];
  const float* bk1 = (const float*)d_in[5];
  const float* wv1 = (const float*)d_in[6];
  const float* bv1 = (const float*)d_in[7];
  const float* wq2 = (const float*)d_in[8];
  const float* bq2 = (const float*)d_in[9];
  const float* wk2 = (const float*)d_in[10];
  const float* bk2 = (const float*)d_in[11];
  const float* wv2 = (const float*)d_in[12];
  const float* bv2 = (const float*)d_in[13];
  const float* wd1 = (const float*)d_in[14];
  const float* bd1 = (const float*)d_in[15];
  const float* wd3 = (const float*)d_in[16];
  const float* bd3 = (const float*)d_in[17];
  const float* g1  = (const float*)d_in[18];
  const float* g2  = (const float*)d_in[19];
  float* out = (float*)d_out;

  // workspace layout (bytes)
  const size_t QB = (size_t)BB * NN * CKD * 2;     // 1 MB each
  const size_t VB = (size_t)BB * NN * CC * 2;      // 8 MB each
  const size_t XB = (size_t)2 * BB * NN * CC * 2;  // 16 MB
  const size_t WPB = (size_t)10 * CC * CC * 2;     // 1.31 MB
  const size_t WQB = (size_t)2 * 320 * CC * 2;     // 320 KB
  char* base = (char*)d_ws;
  unsigned short* Qp1 = (unsigned short*)(base);
  unsigned short* Kp1 = (unsigned short*)(base + QB);
  unsigned short* Qp2 = (unsigned short*)(base + 2 * QB);
  unsigned short* Kp2 = (unsigned short*)(base + 3 * QB);
  unsigned short* Vp1 = (unsigned short*)(base + 4 * QB);
  unsigned short* Vp2 = (unsigned short*)(base + 4 * QB + VB);
  unsigned short* Xp  = (unsigned short*)(base + 4 * QB + 2 * VB);
  unsigned short* Wp  = (unsigned short*)(base + 4 * QB + 2 * VB + XB);
  unsigned short* Wqkv = (unsigned short*)(base + 4 * QB + 2 * VB + XB + WPB);
  float* Bias = (float*)(base + 4 * QB + 2 * VB + XB + WPB + WQB);

  pack_kernel<<<dim3(NN / 64, CC / 64, 9), 256, 0, stream>>>(
      x1, x2, Xp, wd1, wd3, wq1, wk1, wv1, wq2, wk2, wv2,
      bq1, bk1, bv1, bq2, bk2, bv2, Wp, Wqkv, Bias);

  proj_mfma_kernel<<<dim3(2 * BB, NN / 64), 256, 0, stream>>>(
      Xp, Wqkv, Bias, Qp1, Kp1, Vp1, Qp2, Kp2, Vp2);

  attn_kernel<<<dim3(2, BB, NN / 64), 256, 0, stream>>>(
      Qp1, Kp1, Qp2, Kp2, Vp1, Vp2, Xp, Wp, bd1, bd3, x1, x2, g1, g2, out);
}